// Round 4
// baseline (1833.415 us; speedup 1.0000x reference)
//
#include <hip/hip_runtime.h>
#include <hip/hip_bf16.h>
#include <type_traits>
#include <math.h>

typedef __hip_bfloat16 bf16_t;

// Problem constants
#define BB 4
#define LL 2048
#define DM 1024
#define DI 2048
#define NS 16
#define DTR 64
#define DFF 4096
#define MTOK (BB*LL)   // 8192

// ---------- helpers ----------
__device__ __forceinline__ float b2f_lo(unsigned u) {
    union { unsigned x; float f; } c; c.x = u << 16; return c.f;
}
__device__ __forceinline__ float b2f_hi(unsigned u) {
    union { unsigned x; float f; } c; c.x = u & 0xffff0000u; return c.f;
}
__device__ __forceinline__ void unpack8(uint4 v, float* o) {
    o[0] = b2f_lo(v.x); o[1] = b2f_hi(v.x);
    o[2] = b2f_lo(v.y); o[3] = b2f_hi(v.y);
    o[4] = b2f_lo(v.z); o[5] = b2f_hi(v.z);
    o[6] = b2f_lo(v.w); o[7] = b2f_hi(v.w);
}

typedef __attribute__((ext_vector_type(8))) short bf16x8;   // 8 bf16 (4 VGPRs)
typedef __attribute__((ext_vector_type(4))) float f32x4;

__device__ __forceinline__ void gld_lds16(const void* g, void* l) {
    __builtin_amdgcn_global_load_lds(
        (const __attribute__((address_space(1))) void*)g,
        (__attribute__((address_space(3))) void*)l, 16, 0, 0);
}

// ---------- dtype detection ----------
// flag=1: buffers are bf16; flag=0: buffers are fp32.
// For bf16 data, low half-word of each 32-bit word is a plausible N(0,1) bf16
// (exp in [100,140]) with prob ~1. For fp32 data it's mantissa junk (~16%).
__global__ void detect_dtype_kernel(const unsigned* __restrict__ x, int* __restrict__ flag)
{
    __shared__ int cnt;
    if (threadIdx.x == 0) cnt = 0;
    __syncthreads();
    int c = 0;
    for (int i = threadIdx.x; i < 4096; i += 256) {
        unsigned w = x[i];
        int e = (w >> 7) & 0xFF;           // exponent field of LOW half as bf16
        c += (e >= 100 && e <= 140) ? 1 : 0;
    }
    atomicAdd(&cnt, c);
    __syncthreads();
    if (threadIdx.x == 0) *flag = (cnt > 2048) ? 1 : 0;
}

// ---------- canonicalize an input tensor to bf16 (n must be multiple of 8) ----------
__global__ __launch_bounds__(256)
void convert_kernel(const void* __restrict__ src, bf16_t* __restrict__ dst,
                    int n8, const int* __restrict__ flag)
{
    int i = blockIdx.x * 256 + threadIdx.x;
    if (i >= n8) return;
    if (*flag) {                             // already bf16: vector copy
        ((uint4*)dst)[i] = ((const uint4*)src)[i];
    } else {                                 // fp32: round to bf16
        const float4* s = (const float4*)src + (size_t)i * 2;
        float4 a = s[0], b = s[1];
        bf16_t o[8];
        o[0] = __float2bfloat16(a.x); o[1] = __float2bfloat16(a.y);
        o[2] = __float2bfloat16(a.z); o[3] = __float2bfloat16(a.w);
        o[4] = __float2bfloat16(b.x); o[5] = __float2bfloat16(b.y);
        o[6] = __float2bfloat16(b.z); o[7] = __float2bfloat16(b.w);
        ((uint4*)dst)[i] = *(uint4*)o;
    }
}

// ---------- GEMM: C[m,n] = sum_k A[m,k] * W[n,k]  (A row-major [M,K], W row-major [N,K]) ----------
// m97-style: 128x128 tile, BK=64, 256 threads = 4 waves (2x2), each wave 64x64 (4x4 MFMA 16x16x32).
// EPI: 0 none, 1 +bias, 2 +bias+relu, 3 +bias+softplus
// DYN: store dtype chosen at runtime from *oflag (1=bf16, 0=fp32); C treated as base ptr,
//      row offset c_row_off added (element indexing is dtype-scaled via cast).
#define TM 128
#define TN 128
#define TK 64

template <typename OutT, int EPI, bool DYN>
__global__ __launch_bounds__(256, 2)
void gemm_bt(const bf16_t* __restrict__ A, int lda,
             const bf16_t* __restrict__ W, int ldw,
             OutT* __restrict__ C, int ldc,
             const bf16_t* __restrict__ bias,
             int M, int N, int K,
             const int* oflag, int c_row_off)
{
    __shared__ bf16_t sA[TM * TK];
    __shared__ bf16_t sB[TN * TK];

    const int tid  = threadIdx.x;
    const int lane = tid & 63;
    const int wv   = tid >> 6;
    const int m0   = blockIdx.x * TM;
    const int n0   = blockIdx.y * TN;
    const int wm   = (wv >> 1) * 64;
    const int wn   = (wv & 1) * 64;
    const int r16  = lane & 15;
    const int q    = lane >> 4;

    int of = 1;
    if constexpr (DYN) of = *oflag;

    f32x4 acc[4][4] = {};

    for (int k0 = 0; k0 < K; k0 += TK) {
#pragma unroll
        for (int i = 0; i < 4; ++i) {
            int c    = (i * 4 + wv) * 64 + lane;     // chunk id 0..1023
            int row  = c >> 3;
            int col8 = c & 7;
            const bf16_t* ga = A + (size_t)(m0 + row) * lda + k0 + col8 * 8;
            gld_lds16(ga, (char*)sA + (size_t)(i * 4 + wv) * 1024);
            int nrow = n0 + row; if (nrow > N - 1) nrow = N - 1;   // clamp for N=96 edge
            const bf16_t* gb = W + (size_t)nrow * ldw + k0 + col8 * 8;
            gld_lds16(gb, (char*)sB + (size_t)(i * 4 + wv) * 1024);
        }
        __syncthreads();

        const bf16x8* sA8 = (const bf16x8*)sA;
        const bf16x8* sB8 = (const bf16x8*)sB;
#pragma unroll
        for (int kk = 0; kk < 2; ++kk) {
            bf16x8 af[4], bfr[4];
#pragma unroll
            for (int i = 0; i < 4; ++i)
                af[i] = sA8[(wm + i * 16 + r16) * 8 + kk * 4 + q];
#pragma unroll
            for (int j = 0; j < 4; ++j)
                bfr[j] = sB8[(wn + j * 16 + r16) * 8 + kk * 4 + q];
#pragma unroll
            for (int i = 0; i < 4; ++i)
#pragma unroll
                for (int j = 0; j < 4; ++j)
                    acc[i][j] = __builtin_amdgcn_mfma_f32_16x16x32_bf16(
                        af[i], bfr[j], acc[i][j], 0, 0, 0);
        }
        __syncthreads();
    }

    // Epilogue. C/D layout: col = lane&15, row = (lane>>4)*4 + reg
#pragma unroll
    for (int j = 0; j < 4; ++j) {
        int colg = n0 + wn + j * 16 + r16;
        if (colg >= N) continue;
        float bv = 0.f;
        if (EPI >= 1) bv = __bfloat162float(bias[colg]);
#pragma unroll
        for (int i = 0; i < 4; ++i) {
#pragma unroll
            for (int r = 0; r < 4; ++r) {
                int rowg = m0 + wm + i * 16 + q * 4 + r;
                if (rowg >= M) continue;
                float v = acc[i][j][r];
                if (EPI >= 1) v += bv;
                if (EPI == 2) v = v > 0.f ? v : 0.f;
                if (EPI == 3) v = (v > 20.f) ? v : log1pf(__expf(v));
                if constexpr (DYN) {
                    size_t idx = (size_t)(c_row_off + rowg) * ldc + colg;
                    if (of) ((bf16_t*)C)[idx] = __float2bfloat16(v);
                    else    ((float*)C)[idx]  = v;
                } else if constexpr (std::is_same<OutT, float>::value) {
                    C[(size_t)rowg * ldc + colg] = v;
                } else {
                    C[(size_t)rowg * ldc + colg] = __float2bfloat16(v);
                }
            }
        }
    }
}

// ---------- depthwise causal conv (k=4) + bias + SiLU ----------
__global__ __launch_bounds__(256)
void conv_silu_kernel(const bf16_t* __restrict__ u,
                      const bf16_t* __restrict__ cw,
                      const bf16_t* __restrict__ cb,
                      bf16_t* __restrict__ uc,
                      int Mrows)
{
    int idx = blockIdx.x * 256 + threadIdx.x;      // over Mrows * (DI/8)
    int eg  = idx & 255;                           // DI/8 = 256
    int row = idx >> 8;
    if (row >= Mrows) return;
    int t = row & (LL - 1);                        // slice starts at batch boundary
    int b = row >> 11;
    int e0 = eg * 8;

    float wf[32];
    {
        const uint4* wp = (const uint4*)(cw + (size_t)e0 * 4);  // [e][k] flat
        uint4 w0 = wp[0], w1 = wp[1], w2 = wp[2], w3 = wp[3];
        unpack8(w0, wf); unpack8(w1, wf + 8); unpack8(w2, wf + 16); unpack8(w3, wf + 24);
    }
    float bias[8];
    unpack8(*(const uint4*)(cb + e0), bias);

    float uk[4][8];
#pragma unroll
    for (int k = 0; k < 4; ++k) {
        int tt = t - 3 + k;
        if (tt >= 0) {
            uint4 uv = *(const uint4*)(u + (size_t)(b * LL + tt) * DI + e0);
            unpack8(uv, uk[k]);
        } else {
#pragma unroll
            for (int j = 0; j < 8; ++j) uk[k][j] = 0.f;
        }
    }
    bf16_t out8[8];
#pragma unroll
    for (int j = 0; j < 8; ++j) {
        float a = bias[j];
#pragma unroll
        for (int k = 0; k < 4; ++k) a += wf[j * 4 + k] * uk[k][j];
        a = a / (1.f + __expf(-a));              // SiLU
        out8[j] = __float2bfloat16(a);
    }
    *(uint4*)(uc + (size_t)row * DI + e0) = *(uint4*)out8;
}

// ---------- selective scan + gating epilogue ----------
// thread per (b,e): h[16] in registers, sequential over L with 1-step prefetch.
// y = (scan_y + u*D) * silu(z); y written IN-PLACE over z (safe: column-owned).
__global__ __launch_bounds__(64)
void scan_kernel(const bf16_t* __restrict__ uc,
                 const bf16_t* __restrict__ dt,
                 const bf16_t* __restrict__ xdbl,
                 bf16_t* __restrict__ zy,
                 const bf16_t* __restrict__ A_log,
                 const bf16_t* __restrict__ Dp)
{
    int idx = blockIdx.x * 64 + threadIdx.x;   // 0 .. G*DI-1
    int e = idx & (DI - 1);
    int b = idx >> 11;                         // batch within group slice

    float Aa[NS];
#pragma unroll
    for (int n = 0; n < NS; ++n)
        Aa[n] = -__expf(__bfloat162float(A_log[e * NS + n]));
    float Dv = __bfloat162float(Dp[e]);
    float h[NS];
#pragma unroll
    for (int n = 0; n < NS; ++n) h[n] = 0.f;

    const bf16_t* up  = uc   + (size_t)b * LL * DI + e;
    const bf16_t* dp  = dt   + (size_t)b * LL * DI + e;
    const bf16_t* zp  = zy   + (size_t)b * LL * DI + e;
    const bf16_t* bcp = xdbl + (size_t)b * LL * 96 + 64;
    bf16_t*       yp  = zy   + (size_t)b * LL * DI + e;

    float nu  = __bfloat162float(*up);
    float ndt = __bfloat162float(*dp);
    float nz  = __bfloat162float(*zp);
    uint4 nb0 = *(const uint4*)(bcp);
    uint4 nb1 = *(const uint4*)(bcp + 8);
    uint4 nc0 = *(const uint4*)(bcp + 16);
    uint4 nc1 = *(const uint4*)(bcp + 24);

    for (int t = 0; t < LL; ++t) {
        float cu = nu, cdt = ndt, cz = nz;
        uint4 b0 = nb0, b1 = nb1, c0 = nc0, c1 = nc1;
        if (t + 1 < LL) {
            up += DI; dp += DI; zp += DI; bcp += 96;
            nu  = __bfloat162float(*up);
            ndt = __bfloat162float(*dp);
            nz  = __bfloat162float(*zp);           // reads row t+1 before y(t) store
            nb0 = *(const uint4*)(bcp);
            nb1 = *(const uint4*)(bcp + 8);
            nc0 = *(const uint4*)(bcp + 16);
            nc1 = *(const uint4*)(bcp + 24);
        }
        float Bv[NS], Cv[NS];
        unpack8(b0, Bv); unpack8(b1, Bv + 8);
        unpack8(c0, Cv); unpack8(c1, Cv + 8);

        float du = cdt * cu;
        float yv = 0.f;
#pragma unroll
        for (int n = 0; n < NS; ++n) {
            float dA = __expf(cdt * Aa[n]);
            h[n] = dA * h[n] + du * Bv[n];
            yv += h[n] * Cv[n];
        }
        float sil  = cz / (1.f + __expf(-cz));
        float outv = (yv + cu * Dv) * sil;
        *yp = __float2bfloat16(outv);
        yp += DI;
    }
}

// ---------- launcher ----------
extern "C" void kernel_launch(void* const* d_in, const int* in_sizes, int n_in,
                              void* d_out, int out_size, void* d_ws, size_t ws_size,
                              hipStream_t stream)
{
    char* ws = (char*)d_ws;
    int* flag = (int*)ws;
    size_t cur = 256;
    auto alloc = [&](size_t bytes) { bf16_t* p = (bf16_t*)(ws + cur); cur += bytes; return p; };

    // canonical bf16 copies of all inputs (~44.7 MiB)
    bf16_t* xb   = alloc((size_t)MTOK * DM * 2);      // 16 MiB
    bf16_t* w_in = alloc((size_t)2 * DI * DM * 2);    //  8 MiB
    bf16_t* w_o  = alloc((size_t)DM * DI * 2);        //  4 MiB
    bf16_t* w_l1 = alloc((size_t)DFF * DM * 2);       //  8 MiB
    bf16_t* w_l2 = alloc((size_t)DM * DFF * 2);       //  8 MiB
    bf16_t* w_xp = alloc((size_t)96 * DI * 2);        // 384 KiB
    bf16_t* w_dt = alloc((size_t)DI * DTR * 2);       // 256 KiB
    bf16_t* cw   = alloc((size_t)DI * 4 * 2);
    bf16_t* cb   = alloc((size_t)DI * 2);
    bf16_t* dpb  = alloc((size_t)DI * 2);
    bf16_t* alog = alloc((size_t)DI * NS * 2);
    bf16_t* dd   = alloc((size_t)DI * 2);
    bf16_t* l1b  = alloc((size_t)DFF * 2);
    bf16_t* l2b  = alloc((size_t)DM * 2 + 2048);      // pad to 256-mult
    cur = (cur + 255) & ~(size_t)255;
    size_t o_pipe = cur;

    // 0. detect input storage dtype from x
    detect_dtype_kernel<<<1, 256, 0, stream>>>((const unsigned*)d_in[0], flag);

    // canonicalize all inputs
    struct { const void* s; bf16_t* d; size_t n; } cv[14] = {
        { d_in[0],  xb,   (size_t)MTOK * DM },
        { d_in[1],  w_in, (size_t)2 * DI * DM },
        { d_in[9],  w_o,  (size_t)DM * DI },
        { d_in[10], w_l1, (size_t)DFF * DM },
        { d_in[12], w_l2, (size_t)DM * DFF },
        { d_in[4],  w_xp, (size_t)96 * DI },
        { d_in[5],  w_dt, (size_t)DI * DTR },
        { d_in[2],  cw,   (size_t)DI * 4 },
        { d_in[3],  cb,   (size_t)DI },
        { d_in[6],  dpb,  (size_t)DI },
        { d_in[7],  alog, (size_t)DI * NS },
        { d_in[8],  dd,   (size_t)DI },
        { d_in[11], l1b,  (size_t)DFF },
        { d_in[13], l2b,  (size_t)DM },
    };
    for (int i = 0; i < 14; ++i) {
        int n8 = (int)(cv[i].n / 8);
        convert_kernel<<<(n8 + 255) / 256, 256, 0, stream>>>(cv[i].s, cv[i].d, n8, flag);
    }

    // pick batch-group size G by workspace fit
    auto need = [&](int G) {
        return o_pipe + (size_t)G * LL * 96 * 2 + 3 * (size_t)G * LL * DI * 2;
    };
    int G = 1;
    if (ws_size >= need(4)) G = 4; else if (ws_size >= need(2)) G = 2;

    for (int g0 = 0; g0 < BB; g0 += G) {
        const int    Mg      = G * LL;
        const size_t xdbl_sz = (size_t)Mg * 96 * 2;
        const size_t big     = (size_t)Mg * DI * 2;

        bf16_t* xdbl = (bf16_t*)(ws + o_pipe);
        bf16_t* ubuf = (bf16_t*)(ws + o_pipe + xdbl_sz);
        bf16_t* dtb  = ubuf;
        bf16_t* zbuf = (bf16_t*)(ws + o_pipe + xdbl_sz + big);
        bf16_t* uc   = (bf16_t*)(ws + o_pipe + xdbl_sz + 2 * big);
        bf16_t* my   = uc;
        bf16_t* hh   = (bf16_t*)(ws + o_pipe);     // overlaps dead xdbl+ubuf+zbuf

        const bf16_t* x_g = xb + (size_t)g0 * LL * DM;

        dim3 blk(256);
        const int gx = Mg / TM;

        // 1a. in_proj (u half)
        gemm_bt<bf16_t, 0, false><<<dim3(gx, DI / TN), blk, 0, stream>>>(
            x_g, DM, w_in, DM, ubuf, DI, nullptr, Mg, DI, DM, nullptr, 0);
        // 1b. in_proj (z half)
        gemm_bt<bf16_t, 0, false><<<dim3(gx, DI / TN), blk, 0, stream>>>(
            x_g, DM, w_in + (size_t)DI * DM, DM, zbuf, DI, nullptr, Mg, DI, DM, nullptr, 0);
        // 2. depthwise conv + SiLU -> uc
        conv_silu_kernel<<<Mg, 256, 0, stream>>>(ubuf, cw, cb, uc, Mg);
        // 3. x_proj -> xdbl [Mg,96]
        gemm_bt<bf16_t, 0, false><<<dim3(gx, 1), blk, 0, stream>>>(
            uc, DI, w_xp, DI, xdbl, 96, nullptr, Mg, 96, DI, nullptr, 0);
        // 4. dt_proj + softplus -> dtb
        gemm_bt<bf16_t, 3, false><<<dim3(gx, DI / TN), blk, 0, stream>>>(
            xdbl, 96, w_dt, DTR, dtb, DI, dpb, Mg, DI, DTR, nullptr, 0);
        // 5. selective scan + gating; y overwrites zbuf
        scan_kernel<<<(G * DI) / 64, 64, 0, stream>>>(uc, dtb, xdbl, zbuf, alog, dd);
        // 6. out_proj -> my
        gemm_bt<bf16_t, 0, false><<<dim3(gx, DM / TN), blk, 0, stream>>>(
            zbuf, DI, w_o, DI, my, DM, nullptr, Mg, DM, DI, nullptr, 0);
        // 7. lin1 + bias + relu -> hh
        gemm_bt<bf16_t, 2, false><<<dim3(gx, DFF / TN), blk, 0, stream>>>(
            my, DM, w_l1, DM, hh, DFF, l1b, Mg, DFF, DM, nullptr, 0);
        // 8. lin2 + bias -> d_out (dtype per flag), row offset g0*LL
        gemm_bt<bf16_t, 1, true><<<dim3(gx, DM / TN), blk, 0, stream>>>(
            hh, DFF, w_l2, DFF, (bf16_t*)d_out, DM, l2b, Mg, DM, DFF,
            (const int*)ws, g0 * LL);
    }
}

// Round 5
// 934.385 us; speedup vs baseline: 1.9622x; 1.9622x over previous
//
#include <hip/hip_runtime.h>
#include <hip/hip_bf16.h>
#include <type_traits>
#include <math.h>

typedef __hip_bfloat16 bf16_t;

// Problem constants
#define BB 4
#define LL 2048
#define DM 1024
#define DI 2048
#define NS 16
#define DTR 64
#define DFF 4096
#define MTOK (BB*LL)   // 8192
#define NC 16          // scan chunks
#define CL (LL/NC)     // 128 timesteps per chunk

// ---------- helpers ----------
__device__ __forceinline__ float b2f_lo(unsigned u) {
    union { unsigned x; float f; } c; c.x = u << 16; return c.f;
}
__device__ __forceinline__ float b2f_hi(unsigned u) {
    union { unsigned x; float f; } c; c.x = u & 0xffff0000u; return c.f;
}
__device__ __forceinline__ void unpack8(uint4 v, float* o) {
    o[0] = b2f_lo(v.x); o[1] = b2f_hi(v.x);
    o[2] = b2f_lo(v.y); o[3] = b2f_hi(v.y);
    o[4] = b2f_lo(v.z); o[5] = b2f_hi(v.z);
    o[6] = b2f_lo(v.w); o[7] = b2f_hi(v.w);
}

typedef __attribute__((ext_vector_type(8))) short bf16x8;   // 8 bf16 (4 VGPRs)
typedef __attribute__((ext_vector_type(4))) float f32x4;

__device__ __forceinline__ void gld_lds16(const void* g, void* l) {
    __builtin_amdgcn_global_load_lds(
        (const __attribute__((address_space(1))) void*)g,
        (__attribute__((address_space(3))) void*)l, 16, 0, 0);
}

// ---------- dtype detection ----------
// flag=1: buffers are bf16; flag=0: fp32. For bf16 data the low half-word of a
// 32-bit word is a plausible N(0,1) bf16 exponent ~always; for fp32 it's mantissa junk.
__global__ void detect_dtype_kernel(const unsigned* __restrict__ x, int* __restrict__ flag)
{
    __shared__ int cnt;
    if (threadIdx.x == 0) cnt = 0;
    __syncthreads();
    int c = 0;
    for (int i = threadIdx.x; i < 4096; i += 256) {
        unsigned w = x[i];
        int e = (w >> 7) & 0xFF;
        c += (e >= 100 && e <= 140) ? 1 : 0;
    }
    atomicAdd(&cnt, c);
    __syncthreads();
    if (threadIdx.x == 0) *flag = (cnt > 2048) ? 1 : 0;
}

// ---------- canonicalize ALL inputs to bf16 in ONE launch ----------
struct CvtDesc {
    const void* src[14];
    bf16_t*     dst[14];
    int         cum[15];   // prefix sums of n/8
};

__global__ __launch_bounds__(256)
void convert_all(CvtDesc d, const int* __restrict__ flag, int total8)
{
    int i = blockIdx.x * 256 + threadIdx.x;
    if (i >= total8) return;
    int t = 0;
#pragma unroll 1
    while (i >= d.cum[t + 1]) ++t;
    int j = i - d.cum[t];
    if (*flag) {
        ((uint4*)d.dst[t])[j] = ((const uint4*)d.src[t])[j];
    } else {
        const float4* s = (const float4*)d.src[t] + (size_t)j * 2;
        float4 a = s[0], b = s[1];
        bf16_t o[8];
        o[0] = __float2bfloat16(a.x); o[1] = __float2bfloat16(a.y);
        o[2] = __float2bfloat16(a.z); o[3] = __float2bfloat16(a.w);
        o[4] = __float2bfloat16(b.x); o[5] = __float2bfloat16(b.y);
        o[6] = __float2bfloat16(b.z); o[7] = __float2bfloat16(b.w);
        ((uint4*)d.dst[t])[j] = *(uint4*)o;
    }
}

// ---------- GEMM: C[m,n] = sum_k A[m,k] * W[n,k] ----------
#define TM 128
#define TN 128
#define TK 64

template <typename OutT, int EPI, bool DYN>
__global__ __launch_bounds__(256, 2)
void gemm_bt(const bf16_t* __restrict__ A, int lda,
             const bf16_t* __restrict__ W, int ldw,
             OutT* __restrict__ C, int ldc,
             const bf16_t* __restrict__ bias,
             int M, int N, int K,
             const int* oflag, int c_row_off)
{
    __shared__ bf16_t sA[TM * TK];
    __shared__ bf16_t sB[TN * TK];

    const int tid  = threadIdx.x;
    const int lane = tid & 63;
    const int wv   = tid >> 6;
    const int m0   = blockIdx.x * TM;
    const int n0   = blockIdx.y * TN;
    const int wm   = (wv >> 1) * 64;
    const int wn   = (wv & 1) * 64;
    const int r16  = lane & 15;
    const int q    = lane >> 4;

    int of = 1;
    if constexpr (DYN) of = *oflag;

    f32x4 acc[4][4] = {};

    for (int k0 = 0; k0 < K; k0 += TK) {
#pragma unroll
        for (int i = 0; i < 4; ++i) {
            int c    = (i * 4 + wv) * 64 + lane;
            int row  = c >> 3;
            int col8 = c & 7;
            const bf16_t* ga = A + (size_t)(m0 + row) * lda + k0 + col8 * 8;
            gld_lds16(ga, (char*)sA + (size_t)(i * 4 + wv) * 1024);
            int nrow = n0 + row; if (nrow > N - 1) nrow = N - 1;
            const bf16_t* gb = W + (size_t)nrow * ldw + k0 + col8 * 8;
            gld_lds16(gb, (char*)sB + (size_t)(i * 4 + wv) * 1024);
        }
        __syncthreads();

        const bf16x8* sA8 = (const bf16x8*)sA;
        const bf16x8* sB8 = (const bf16x8*)sB;
#pragma unroll
        for (int kk = 0; kk < 2; ++kk) {
            bf16x8 af[4], bfr[4];
#pragma unroll
            for (int i = 0; i < 4; ++i)
                af[i] = sA8[(wm + i * 16 + r16) * 8 + kk * 4 + q];
#pragma unroll
            for (int j = 0; j < 4; ++j)
                bfr[j] = sB8[(wn + j * 16 + r16) * 8 + kk * 4 + q];
#pragma unroll
            for (int i = 0; i < 4; ++i)
#pragma unroll
                for (int j = 0; j < 4; ++j)
                    acc[i][j] = __builtin_amdgcn_mfma_f32_16x16x32_bf16(
                        af[i], bfr[j], acc[i][j], 0, 0, 0);
        }
        __syncthreads();
    }

    // Epilogue. C/D layout: col = lane&15, row = (lane>>4)*4 + reg
#pragma unroll
    for (int j = 0; j < 4; ++j) {
        int colg = n0 + wn + j * 16 + r16;
        if (colg >= N) continue;
        float bv = 0.f;
        if (EPI >= 1) bv = __bfloat162float(bias[colg]);
#pragma unroll
        for (int i = 0; i < 4; ++i) {
#pragma unroll
            for (int r = 0; r < 4; ++r) {
                int rowg = m0 + wm + i * 16 + q * 4 + r;
                if (rowg >= M) continue;
                float v = acc[i][j][r];
                if (EPI >= 1) v += bv;
                if (EPI == 2) v = v > 0.f ? v : 0.f;
                if (EPI == 3) v = (v > 20.f) ? v : log1pf(__expf(v));
                if constexpr (DYN) {
                    size_t idx = (size_t)(c_row_off + rowg) * ldc + colg;
                    if (of) ((bf16_t*)C)[idx] = __float2bfloat16(v);
                    else    ((float*)C)[idx]  = v;
                } else if constexpr (std::is_same<OutT, float>::value) {
                    C[(size_t)rowg * ldc + colg] = v;
                } else {
                    C[(size_t)rowg * ldc + colg] = __float2bfloat16(v);
                }
            }
        }
    }
}

// ---------- depthwise causal conv (k=4) + bias + SiLU ----------
__global__ __launch_bounds__(256)
void conv_silu_kernel(const bf16_t* __restrict__ u,
                      const bf16_t* __restrict__ cw,
                      const bf16_t* __restrict__ cb,
                      bf16_t* __restrict__ uc,
                      int Mrows)
{
    int idx = blockIdx.x * 256 + threadIdx.x;
    int eg  = idx & 255;
    int row = idx >> 8;
    if (row >= Mrows) return;
    int t = row & (LL - 1);
    int b = row >> 11;
    int e0 = eg * 8;

    float wf[32];
    {
        const uint4* wp = (const uint4*)(cw + (size_t)e0 * 4);
        uint4 w0 = wp[0], w1 = wp[1], w2 = wp[2], w3 = wp[3];
        unpack8(w0, wf); unpack8(w1, wf + 8); unpack8(w2, wf + 16); unpack8(w3, wf + 24);
    }
    float bias[8];
    unpack8(*(const uint4*)(cb + e0), bias);

    float uk[4][8];
#pragma unroll
    for (int k = 0; k < 4; ++k) {
        int tt = t - 3 + k;
        if (tt >= 0) {
            uint4 uv = *(const uint4*)(u + (size_t)(b * LL + tt) * DI + e0);
            unpack8(uv, uk[k]);
        } else {
#pragma unroll
            for (int j = 0; j < 8; ++j) uk[k][j] = 0.f;
        }
    }
    bf16_t out8[8];
#pragma unroll
    for (int j = 0; j < 8; ++j) {
        float a = bias[j];
#pragma unroll
        for (int k = 0; k < 4; ++k) a += wf[j * 4 + k] * uk[k][j];
        a = a / (1.f + __expf(-a));
        out8[j] = __float2bfloat16(a);
    }
    *(uint4*)(uc + (size_t)row * DI + e0) = *(uint4*)out8;
}

// ---------- chunked parallel scan: pass 1 (per-chunk A_prod, h_fin) ----------
// thread = (chunk, b, e); NC*G*DI threads. h local init 0; A_prod = exp(Aa*sum(dt)).
__global__ __launch_bounds__(256)
void scan_pass1(const bf16_t* __restrict__ uc, const bf16_t* __restrict__ dt,
                const bf16_t* __restrict__ xdbl, const bf16_t* __restrict__ A_log,
                float* __restrict__ aprod, float* __restrict__ hfin, int lgG)
{
    int idx = blockIdx.x * 256 + threadIdx.x;
    int e = idx & (DI - 1);
    int rem = idx >> 11;
    int b = rem & ((1 << lgG) - 1);
    int chunk = rem >> lgG;

    float Aa[NS];
#pragma unroll
    for (int n = 0; n < NS; ++n)
        Aa[n] = -__expf(__bfloat162float(A_log[e * NS + n]));

    float h[NS];
#pragma unroll
    for (int n = 0; n < NS; ++n) h[n] = 0.f;
    float S = 0.f;

    int t0 = chunk * CL;
    const bf16_t* up  = uc   + ((size_t)b * LL + t0) * DI + e;
    const bf16_t* dp  = dt   + ((size_t)b * LL + t0) * DI + e;
    const bf16_t* bcp = xdbl + ((size_t)b * LL + t0) * 96 + 64;

    float nu  = __bfloat162float(*up);
    float ndt = __bfloat162float(*dp);
    uint4 nb0 = *(const uint4*)(bcp);
    uint4 nb1 = *(const uint4*)(bcp + 8);

    for (int t = 0; t < CL; ++t) {
        float cu = nu, cdt = ndt;
        uint4 b0 = nb0, b1 = nb1;
        if (t + 1 < CL) {
            up += DI; dp += DI; bcp += 96;
            nu  = __bfloat162float(*up);
            ndt = __bfloat162float(*dp);
            nb0 = *(const uint4*)(bcp);
            nb1 = *(const uint4*)(bcp + 8);
        }
        float Bv[NS];
        unpack8(b0, Bv); unpack8(b1, Bv + 8);
        float du = cdt * cu;
        S += cdt;
#pragma unroll
        for (int n = 0; n < NS; ++n) {
            float dA = __expf(cdt * Aa[n]);
            h[n] = dA * h[n] + du * Bv[n];
        }
    }
    size_t base = (size_t)(b * NC + chunk) * NS * DI + e;
#pragma unroll
    for (int n = 0; n < NS; ++n) aprod[base + (size_t)n * DI] = __expf(Aa[n] * S);
#pragma unroll
    for (int n = 0; n < NS; ++n) hfin[base + (size_t)n * DI] = h[n];
}

// ---------- pass 2: summary scan over chunks; h_in overwrites hfin in place ----------
__global__ __launch_bounds__(256)
void scan_pass2(const float* __restrict__ aprod, float* __restrict__ hfin)
{
    int idx = blockIdx.x * 256 + threadIdx.x;   // G*DI*NS
    int e = idx & (DI - 1);
    int rem = idx >> 11;
    int n = rem & (NS - 1);
    int b = rem >> 4;
    float h = 0.f;
    for (int c = 0; c < NC; ++c) {
        size_t a = ((size_t)(b * NC + c) * NS + n) * DI + e;
        float Ap = aprod[a];
        float hf = hfin[a];
        hfin[a] = h;             // h_in for chunk c
        h = Ap * h + hf;
    }
}

// ---------- pass 3: replay chunk from h_in, full y + gating; y over z in place ----------
__global__ __launch_bounds__(256)
void scan_pass3(const bf16_t* __restrict__ uc, const bf16_t* __restrict__ dt,
                const bf16_t* __restrict__ xdbl, bf16_t* __restrict__ zy,
                const bf16_t* __restrict__ A_log, const bf16_t* __restrict__ Dp,
                const float* __restrict__ hin, int lgG)
{
    int idx = blockIdx.x * 256 + threadIdx.x;
    int e = idx & (DI - 1);
    int rem = idx >> 11;
    int b = rem & ((1 << lgG) - 1);
    int chunk = rem >> lgG;

    float Aa[NS];
#pragma unroll
    for (int n = 0; n < NS; ++n)
        Aa[n] = -__expf(__bfloat162float(A_log[e * NS + n]));
    float Dv = __bfloat162float(Dp[e]);

    size_t base = (size_t)(b * NC + chunk) * NS * DI + e;
    float h[NS];
#pragma unroll
    for (int n = 0; n < NS; ++n) h[n] = hin[base + (size_t)n * DI];

    int t0 = chunk * CL;
    const bf16_t* up  = uc   + ((size_t)b * LL + t0) * DI + e;
    const bf16_t* dp  = dt   + ((size_t)b * LL + t0) * DI + e;
    const bf16_t* zp  = zy   + ((size_t)b * LL + t0) * DI + e;
    const bf16_t* bcp = xdbl + ((size_t)b * LL + t0) * 96 + 64;
    bf16_t*       yp  = zy   + ((size_t)b * LL + t0) * DI + e;

    float nu  = __bfloat162float(*up);
    float ndt = __bfloat162float(*dp);
    float nz  = __bfloat162float(*zp);
    uint4 nb0 = *(const uint4*)(bcp);
    uint4 nb1 = *(const uint4*)(bcp + 8);
    uint4 nc0 = *(const uint4*)(bcp + 16);
    uint4 nc1 = *(const uint4*)(bcp + 24);

    for (int t = 0; t < CL; ++t) {
        float cu = nu, cdt = ndt, cz = nz;
        uint4 b0 = nb0, b1 = nb1, c0 = nc0, c1 = nc1;
        if (t + 1 < CL) {
            up += DI; dp += DI; zp += DI; bcp += 96;
            nu  = __bfloat162float(*up);
            ndt = __bfloat162float(*dp);
            nz  = __bfloat162float(*zp);     // own rows only: read-before-overwrite safe
            nb0 = *(const uint4*)(bcp);
            nb1 = *(const uint4*)(bcp + 8);
            nc0 = *(const uint4*)(bcp + 16);
            nc1 = *(const uint4*)(bcp + 24);
        }
        float Bv[NS], Cv[NS];
        unpack8(b0, Bv); unpack8(b1, Bv + 8);
        unpack8(c0, Cv); unpack8(c1, Cv + 8);

        float du = cdt * cu;
        float yv = 0.f;
#pragma unroll
        for (int n = 0; n < NS; ++n) {
            float dA = __expf(cdt * Aa[n]);
            h[n] = dA * h[n] + du * Bv[n];
            yv += h[n] * Cv[n];
        }
        float sil  = cz / (1.f + __expf(-cz));
        float outv = (yv + cu * Dv) * sil;
        *yp = __float2bfloat16(outv);
        yp += DI;
    }
}

// ---------- serial scan fallback (ws too small for chunk scratch) ----------
__global__ __launch_bounds__(64)
void scan_kernel(const bf16_t* __restrict__ uc,
                 const bf16_t* __restrict__ dt,
                 const bf16_t* __restrict__ xdbl,
                 bf16_t* __restrict__ zy,
                 const bf16_t* __restrict__ A_log,
                 const bf16_t* __restrict__ Dp)
{
    int idx = blockIdx.x * 64 + threadIdx.x;
    int e = idx & (DI - 1);
    int b = idx >> 11;

    float Aa[NS];
#pragma unroll
    for (int n = 0; n < NS; ++n)
        Aa[n] = -__expf(__bfloat162float(A_log[e * NS + n]));
    float Dv = __bfloat162float(Dp[e]);
    float h[NS];
#pragma unroll
    for (int n = 0; n < NS; ++n) h[n] = 0.f;

    const bf16_t* up  = uc   + (size_t)b * LL * DI + e;
    const bf16_t* dp  = dt   + (size_t)b * LL * DI + e;
    const bf16_t* zp  = zy   + (size_t)b * LL * DI + e;
    const bf16_t* bcp = xdbl + (size_t)b * LL * 96 + 64;
    bf16_t*       yp  = zy   + (size_t)b * LL * DI + e;

    float nu  = __bfloat162float(*up);
    float ndt = __bfloat162float(*dp);
    float nz  = __bfloat162float(*zp);
    uint4 nb0 = *(const uint4*)(bcp);
    uint4 nb1 = *(const uint4*)(bcp + 8);
    uint4 nc0 = *(const uint4*)(bcp + 16);
    uint4 nc1 = *(const uint4*)(bcp + 24);

    for (int t = 0; t < LL; ++t) {
        float cu = nu, cdt = ndt, cz = nz;
        uint4 b0 = nb0, b1 = nb1, c0 = nc0, c1 = nc1;
        if (t + 1 < LL) {
            up += DI; dp += DI; zp += DI; bcp += 96;
            nu  = __bfloat162float(*up);
            ndt = __bfloat162float(*dp);
            nz  = __bfloat162float(*zp);
            nb0 = *(const uint4*)(bcp);
            nb1 = *(const uint4*)(bcp + 8);
            nc0 = *(const uint4*)(bcp + 16);
            nc1 = *(const uint4*)(bcp + 24);
        }
        float Bv[NS], Cv[NS];
        unpack8(b0, Bv); unpack8(b1, Bv + 8);
        unpack8(c0, Cv); unpack8(c1, Cv + 8);

        float du = cdt * cu;
        float yv = 0.f;
#pragma unroll
        for (int n = 0; n < NS; ++n) {
            float dA = __expf(cdt * Aa[n]);
            h[n] = dA * h[n] + du * Bv[n];
            yv += h[n] * Cv[n];
        }
        float sil  = cz / (1.f + __expf(-cz));
        float outv = (yv + cu * Dv) * sil;
        *yp = __float2bfloat16(outv);
        yp += DI;
    }
}

// ---------- launcher ----------
extern "C" void kernel_launch(void* const* d_in, const int* in_sizes, int n_in,
                              void* d_out, int out_size, void* d_ws, size_t ws_size,
                              hipStream_t stream)
{
    char* ws = (char*)d_ws;
    int* flag = (int*)ws;
    size_t cur = 256;
    auto alloc = [&](size_t bytes) { bf16_t* p = (bf16_t*)(ws + cur); cur += bytes; return p; };

    // canonical bf16 copies of all inputs (~44.7 MiB)
    bf16_t* xb   = alloc((size_t)MTOK * DM * 2);      // 16 MiB   (dead after in_proj when G==4)
    bf16_t* w_in = alloc((size_t)2 * DI * DM * 2);    //  8 MiB   (dead after in_proj)
    bf16_t* w_o  = alloc((size_t)DM * DI * 2);
    bf16_t* w_l1 = alloc((size_t)DFF * DM * 2);
    bf16_t* w_l2 = alloc((size_t)DM * DFF * 2);
    bf16_t* w_xp = alloc((size_t)96 * DI * 2);
    bf16_t* w_dt = alloc((size_t)DI * DTR * 2);
    bf16_t* cw   = alloc((size_t)DI * 4 * 2);
    bf16_t* cb   = alloc((size_t)DI * 2);
    bf16_t* dpb  = alloc((size_t)DI * 2);
    bf16_t* alog = alloc((size_t)DI * NS * 2);
    bf16_t* dd   = alloc((size_t)DI * 2);
    bf16_t* l1b  = alloc((size_t)DFF * 2);
    bf16_t* l2b  = alloc((size_t)DM * 2 + 2048);
    cur = (cur + 255) & ~(size_t)255;
    const size_t o_pipe = cur;

    // 0. detect input storage dtype from x
    detect_dtype_kernel<<<1, 256, 0, stream>>>((const unsigned*)d_in[0], flag);

    // 1 launch: canonicalize all 14 inputs
    {
        CvtDesc d;
        const void* ss[14] = { d_in[0], d_in[1], d_in[9], d_in[10], d_in[12], d_in[4],
                               d_in[5], d_in[2], d_in[3], d_in[6], d_in[7], d_in[8],
                               d_in[11], d_in[13] };
        bf16_t* dd_[14]    = { xb, w_in, w_o, w_l1, w_l2, w_xp,
                               w_dt, cw, cb, dpb, alog, dd, l1b, l2b };
        size_t  nn[14]     = { (size_t)MTOK*DM, (size_t)2*DI*DM, (size_t)DM*DI,
                               (size_t)DFF*DM, (size_t)DM*DFF, (size_t)96*DI,
                               (size_t)DI*DTR, (size_t)DI*4, (size_t)DI, (size_t)DI,
                               (size_t)DI*NS, (size_t)DI, (size_t)DFF, (size_t)DM };
        int c = 0; d.cum[0] = 0;
        for (int i = 0; i < 14; ++i) {
            d.src[i] = ss[i]; d.dst[i] = dd_[i];
            c += (int)(nn[i] / 8); d.cum[i + 1] = c;
        }
        convert_all<<<(c + 255) / 256, 256, 0, stream>>>(d, flag, c);
    }

    // workspace plan
    auto pipe = [&](int G) {
        return (size_t)G * LL * 96 * 2 + 3ull * G * LL * DI * 2;
    };
    auto scr = [&](int G) { return 2ull * G * NC * NS * DI * 4; };  // aprod + hfin

    int G; bool chunked; size_t scr_off = 0;
    if      (ws_size >= o_pipe + pipe(4) + scr(4)) { G = 4; chunked = true;  scr_off = o_pipe + pipe(4); }
    else if (ws_size >= o_pipe + pipe(4))          { G = 4; chunked = true;  scr_off = 256; } // over dead xb+w_in (25.2MB > 16.8MB)
    else if (ws_size >= o_pipe + pipe(2) + scr(2)) { G = 2; chunked = true;  scr_off = o_pipe + pipe(2); }
    else if (ws_size >= o_pipe + pipe(1) + scr(1)) { G = 1; chunked = true;  scr_off = o_pipe + pipe(1); }
    else if (ws_size >= o_pipe + pipe(2))          { G = 2; chunked = false; }
    else                                           { G = 1; chunked = false; }
    const int lgG = (G == 4) ? 2 : (G == 2 ? 1 : 0);

    for (int g0 = 0; g0 < BB; g0 += G) {
        const int    Mg      = G * LL;
        const size_t xdbl_sz = (size_t)Mg * 96 * 2;
        const size_t big     = (size_t)Mg * DI * 2;

        bf16_t* xdbl = (bf16_t*)(ws + o_pipe);
        bf16_t* ubuf = (bf16_t*)(ws + o_pipe + xdbl_sz);
        bf16_t* dtb  = ubuf;
        bf16_t* zbuf = (bf16_t*)(ws + o_pipe + xdbl_sz + big);
        bf16_t* uc   = (bf16_t*)(ws + o_pipe + xdbl_sz + 2 * big);
        bf16_t* my   = uc;
        bf16_t* hh   = (bf16_t*)(ws + o_pipe);

        const bf16_t* x_g = xb + (size_t)g0 * LL * DM;

        dim3 blk(256);
        const int gx = Mg / TM;

        // 1a/1b. in_proj halves
        gemm_bt<bf16_t, 0, false><<<dim3(gx, DI / TN), blk, 0, stream>>>(
            x_g, DM, w_in, DM, ubuf, DI, nullptr, Mg, DI, DM, nullptr, 0);
        gemm_bt<bf16_t, 0, false><<<dim3(gx, DI / TN), blk, 0, stream>>>(
            x_g, DM, w_in + (size_t)DI * DM, DM, zbuf, DI, nullptr, Mg, DI, DM, nullptr, 0);
        // 2. depthwise conv + SiLU -> uc
        conv_silu_kernel<<<Mg, 256, 0, stream>>>(ubuf, cw, cb, uc, Mg);
        // 3. x_proj -> xdbl
        gemm_bt<bf16_t, 0, false><<<dim3(gx, 1), blk, 0, stream>>>(
            uc, DI, w_xp, DI, xdbl, 96, nullptr, Mg, 96, DI, nullptr, 0);
        // 4. dt_proj + softplus -> dtb
        gemm_bt<bf16_t, 3, false><<<dim3(gx, DI / TN), blk, 0, stream>>>(
            xdbl, 96, w_dt, DTR, dtb, DI, dpb, Mg, DI, DTR, nullptr, 0);
        // 5. selective scan + gating; y overwrites zbuf
        if (chunked) {
            float* aprod = (float*)(ws + scr_off);
            float* hfin  = (float*)(ws + scr_off + (size_t)G * NC * NS * DI * 4);
            scan_pass1<<<G * 128, 256, 0, stream>>>(uc, dtb, xdbl, alog, aprod, hfin, lgG);
            scan_pass2<<<G * 128, 256, 0, stream>>>(aprod, hfin);
            scan_pass3<<<G * 128, 256, 0, stream>>>(uc, dtb, xdbl, zbuf, alog, dd, hfin, lgG);
        } else {
            scan_kernel<<<(G * DI) / 64, 64, 0, stream>>>(uc, dtb, xdbl, zbuf, alog, dd);
        }
        // 6. out_proj -> my
        gemm_bt<bf16_t, 0, false><<<dim3(gx, DM / TN), blk, 0, stream>>>(
            zbuf, DI, w_o, DI, my, DM, nullptr, Mg, DM, DI, nullptr, 0);
        // 7. lin1 + bias + relu -> hh
        gemm_bt<bf16_t, 2, false><<<dim3(gx, DFF / TN), blk, 0, stream>>>(
            my, DM, w_l1, DM, hh, DFF, l1b, Mg, DFF, DM, nullptr, 0);
        // 8. lin2 + bias -> d_out (dtype per flag)
        gemm_bt<bf16_t, 1, true><<<dim3(gx, DM / TN), blk, 0, stream>>>(
            hh, DFF, w_l2, DFF, (bf16_t*)d_out, DM, l2b, Mg, DM, DFF,
            (const int*)ws, g0 * LL);
    }
}

// Round 6
// 767.017 us; speedup vs baseline: 2.3903x; 1.2182x over previous
//
#include <hip/hip_runtime.h>
#include <hip/hip_bf16.h>
#include <type_traits>
#include <math.h>

typedef __hip_bfloat16 bf16_t;

// Problem constants
#define BB 4
#define LL 2048
#define DM 1024
#define DI 2048
#define NS 16
#define DTR 64
#define DFF 4096
#define MTOK (BB*LL)   // 8192
#define NC 16          // scan chunks
#define CL (LL/NC)     // 128 timesteps per chunk
#define KS 4           // x_proj split-K factor

// ---------- helpers ----------
__device__ __forceinline__ float b2f_lo(unsigned u) {
    union { unsigned x; float f; } c; c.x = u << 16; return c.f;
}
__device__ __forceinline__ float b2f_hi(unsigned u) {
    union { unsigned x; float f; } c; c.x = u & 0xffff0000u; return c.f;
}
__device__ __forceinline__ void unpack8(uint4 v, float* o) {
    o[0] = b2f_lo(v.x); o[1] = b2f_hi(v.x);
    o[2] = b2f_lo(v.y); o[3] = b2f_hi(v.y);
    o[4] = b2f_lo(v.z); o[5] = b2f_hi(v.z);
    o[6] = b2f_lo(v.w); o[7] = b2f_hi(v.w);
}

typedef __attribute__((ext_vector_type(8))) short bf16x8;
typedef __attribute__((ext_vector_type(4))) float f32x4;

__device__ __forceinline__ void gld_lds16(const void* g, void* l) {
    __builtin_amdgcn_global_load_lds(
        (const __attribute__((address_space(1))) void*)g,
        (__attribute__((address_space(3))) void*)l, 16, 0, 0);
}

// ---------- dtype detection (bf16 vs fp32 input buffers) ----------
__global__ void detect_dtype_kernel(const unsigned* __restrict__ x, int* __restrict__ flag)
{
    __shared__ int cnt;
    if (threadIdx.x == 0) cnt = 0;
    __syncthreads();
    int c = 0;
    for (int i = threadIdx.x; i < 4096; i += 256) {
        unsigned w = x[i];
        int e = (w >> 7) & 0xFF;
        c += (e >= 100 && e <= 140) ? 1 : 0;
    }
    atomicAdd(&cnt, c);
    __syncthreads();
    if (threadIdx.x == 0) *flag = (cnt > 2048) ? 1 : 0;
}

// ---------- canonicalize ALL inputs to bf16 in ONE launch ----------
struct CvtDesc {
    const void* src[14];
    bf16_t*     dst[14];
    int         cum[15];
};

__global__ __launch_bounds__(256)
void convert_all(CvtDesc d, const int* __restrict__ flag, int total8)
{
    int i = blockIdx.x * 256 + threadIdx.x;
    if (i >= total8) return;
    int t = 0;
#pragma unroll 1
    while (i >= d.cum[t + 1]) ++t;
    int j = i - d.cum[t];
    if (*flag) {
        ((uint4*)d.dst[t])[j] = ((const uint4*)d.src[t])[j];
    } else {
        const float4* s = (const float4*)d.src[t] + (size_t)j * 2;
        float4 a = s[0], b = s[1];
        bf16_t o[8];
        o[0] = __float2bfloat16(a.x); o[1] = __float2bfloat16(a.y);
        o[2] = __float2bfloat16(a.z); o[3] = __float2bfloat16(a.w);
        o[4] = __float2bfloat16(b.x); o[5] = __float2bfloat16(b.y);
        o[6] = __float2bfloat16(b.z); o[7] = __float2bfloat16(b.w);
        ((uint4*)d.dst[t])[j] = *(uint4*)o;
    }
}

// ---------- GEMM: C[m,n] = sum_k A[m,k] * W[n,k] ----------
// EPI: 0 none, 1 +bias, 2 +bias+relu, 3 +bias+softplus
// DYN: output dtype from *oflag (final lin2 -> d_out)
// EDGE: enable M/N bounds checks (off for all exact-tile shapes)
// C2/nsplit: optional split output (in_proj): colg < nsplit -> C, else C2 at colg-nsplit
#define TM 128
#define TN 128
#define TK 64

template <typename OutT, int EPI, bool DYN, bool EDGE>
__global__ __launch_bounds__(256, 2)
void gemm_bt(const bf16_t* __restrict__ A, int lda,
             const bf16_t* __restrict__ W, int ldw,
             OutT* __restrict__ C, int ldc,
             OutT* __restrict__ C2, int nsplit,
             const bf16_t* __restrict__ bias,
             int M, int N, int K,
             const int* oflag, int c_row_off)
{
    __shared__ bf16_t sA[TM * TK];
    __shared__ bf16_t sB[TN * TK];

    const int tid  = threadIdx.x;
    const int lane = tid & 63;
    const int wv   = tid >> 6;
    const int m0   = blockIdx.x * TM;
    const int n0   = blockIdx.y * TN;
    const int wm   = (wv >> 1) * 64;
    const int wn   = (wv & 1) * 64;
    const int r16  = lane & 15;
    const int q    = lane >> 4;

    int of = 1;
    if constexpr (DYN) of = *oflag;

    f32x4 acc[4][4] = {};

    for (int k0 = 0; k0 < K; k0 += TK) {
#pragma unroll
        for (int i = 0; i < 4; ++i) {
            int c    = (i * 4 + wv) * 64 + lane;
            int row  = c >> 3;
            int col8 = c & 7;
            const bf16_t* ga = A + (size_t)(m0 + row) * lda + k0 + col8 * 8;
            gld_lds16(ga, (char*)sA + (size_t)(i * 4 + wv) * 1024);
            int nrow = n0 + row;
            if (EDGE && nrow > N - 1) nrow = N - 1;
            const bf16_t* gb = W + (size_t)nrow * ldw + k0 + col8 * 8;
            gld_lds16(gb, (char*)sB + (size_t)(i * 4 + wv) * 1024);
        }
        __syncthreads();

        const bf16x8* sA8 = (const bf16x8*)sA;
        const bf16x8* sB8 = (const bf16x8*)sB;
#pragma unroll
        for (int kk = 0; kk < 2; ++kk) {
            bf16x8 af[4], bfr[4];
#pragma unroll
            for (int i = 0; i < 4; ++i)
                af[i] = sA8[(wm + i * 16 + r16) * 8 + kk * 4 + q];
#pragma unroll
            for (int j = 0; j < 4; ++j)
                bfr[j] = sB8[(wn + j * 16 + r16) * 8 + kk * 4 + q];
#pragma unroll
            for (int i = 0; i < 4; ++i)
#pragma unroll
                for (int j = 0; j < 4; ++j)
                    acc[i][j] = __builtin_amdgcn_mfma_f32_16x16x32_bf16(
                        af[i], bfr[j], acc[i][j], 0, 0, 0);
        }
        __syncthreads();
    }

    // split-output select (block-uniform)
    OutT* Cb = C;
    int csub = 0;
    if (C2 != nullptr && n0 >= nsplit) { Cb = C2; csub = nsplit; }

    // Epilogue. C/D layout: col = lane&15, row = (lane>>4)*4 + reg
#pragma unroll
    for (int j = 0; j < 4; ++j) {
        int colg = n0 + wn + j * 16 + r16;
        if (EDGE && colg >= N) continue;
        float bv = 0.f;
        if (EPI >= 1) bv = __bfloat162float(bias[colg]);
#pragma unroll
        for (int i = 0; i < 4; ++i) {
#pragma unroll
            for (int r = 0; r < 4; ++r) {
                int rowg = m0 + wm + i * 16 + q * 4 + r;
                if (EDGE && rowg >= M) continue;
                float v = acc[i][j][r];
                if (EPI >= 1) v += bv;
                if (EPI == 2) v = v > 0.f ? v : 0.f;
                if (EPI == 3) v = (v > 20.f) ? v : log1pf(__expf(v));
                if constexpr (DYN) {
                    size_t idx = (size_t)(c_row_off + rowg) * ldc + colg;
                    if (of) ((bf16_t*)Cb)[idx] = __float2bfloat16(v);
                    else    ((float*)Cb)[idx]  = v;
                } else if constexpr (std::is_same<OutT, float>::value) {
                    Cb[(size_t)rowg * ldc + (colg - csub)] = v;
                } else {
                    Cb[(size_t)rowg * ldc + (colg - csub)] = __float2bfloat16(v);
                }
            }
        }
    }
}

// ---------- x_proj split-K GEMM: part[z] = uc @ w_xp^T over K-chunk z ----------
// M x 96, K=2048 split into KS chunks of 512 (8 TK-iters each). fp32 partials.
__global__ __launch_bounds__(256, 2)
void gemm_xproj_splitk(const bf16_t* __restrict__ A,
                       const bf16_t* __restrict__ W,
                       float* __restrict__ part, int M)
{
    __shared__ bf16_t sA[TM * TK];
    __shared__ bf16_t sB[TN * TK];

    const int tid  = threadIdx.x;
    const int lane = tid & 63;
    const int wv   = tid >> 6;
    const int m0   = blockIdx.x * TM;
    const int kz   = blockIdx.z;
    const int wm   = (wv >> 1) * 64;
    const int wn   = (wv & 1) * 64;
    const int r16  = lane & 15;
    const int q    = lane >> 4;

    f32x4 acc[4][4] = {};

    const int kbeg = kz * (2048 / KS);
    for (int k0 = kbeg; k0 < kbeg + 2048 / KS; k0 += TK) {
#pragma unroll
        for (int i = 0; i < 4; ++i) {
            int c    = (i * 4 + wv) * 64 + lane;
            int row  = c >> 3;
            int col8 = c & 7;
            const bf16_t* ga = A + (size_t)(m0 + row) * DI + k0 + col8 * 8;
            gld_lds16(ga, (char*)sA + (size_t)(i * 4 + wv) * 1024);
            int nrow = row; if (nrow > 95) nrow = 95;
            const bf16_t* gb = W + (size_t)nrow * DI + k0 + col8 * 8;
            gld_lds16(gb, (char*)sB + (size_t)(i * 4 + wv) * 1024);
        }
        __syncthreads();

        const bf16x8* sA8 = (const bf16x8*)sA;
        const bf16x8* sB8 = (const bf16x8*)sB;
#pragma unroll
        for (int kk = 0; kk < 2; ++kk) {
            bf16x8 af[4], bfr[4];
#pragma unroll
            for (int i = 0; i < 4; ++i)
                af[i] = sA8[(wm + i * 16 + r16) * 8 + kk * 4 + q];
#pragma unroll
            for (int j = 0; j < 4; ++j)
                bfr[j] = sB8[(wn + j * 16 + r16) * 8 + kk * 4 + q];
#pragma unroll
            for (int i = 0; i < 4; ++i)
#pragma unroll
                for (int j = 0; j < 4; ++j)
                    acc[i][j] = __builtin_amdgcn_mfma_f32_16x16x32_bf16(
                        af[i], bfr[j], acc[i][j], 0, 0, 0);
        }
        __syncthreads();
    }

#pragma unroll
    for (int j = 0; j < 4; ++j) {
        int colg = wn + j * 16 + r16;
        if (colg >= 96) continue;
#pragma unroll
        for (int i = 0; i < 4; ++i) {
#pragma unroll
            for (int r = 0; r < 4; ++r) {
                int rowg = m0 + wm + i * 16 + q * 4 + r;
                part[((size_t)kz * M + rowg) * 96 + colg] = acc[i][j][r];
            }
        }
    }
}

__global__ __launch_bounds__(256)
void xproj_reduce(const float* __restrict__ part, bf16_t* __restrict__ xdbl, int M)
{
    int i = blockIdx.x * 256 + threadIdx.x;
    int n = M * 96;
    if (i >= n) return;
    float s = part[i] + part[(size_t)n + i] + part[2 * (size_t)n + i] + part[3 * (size_t)n + i];
    xdbl[i] = __float2bfloat16(s);
}

// ---------- depthwise causal conv (k=4) + bias + SiLU ----------
__global__ __launch_bounds__(256)
void conv_silu_kernel(const bf16_t* __restrict__ u,
                      const bf16_t* __restrict__ cw,
                      const bf16_t* __restrict__ cb,
                      bf16_t* __restrict__ uc,
                      int Mrows)
{
    int idx = blockIdx.x * 256 + threadIdx.x;
    int eg  = idx & 255;
    int row = idx >> 8;
    if (row >= Mrows) return;
    int t = row & (LL - 1);
    int b = row >> 11;
    int e0 = eg * 8;

    float wf[32];
    {
        const uint4* wp = (const uint4*)(cw + (size_t)e0 * 4);
        uint4 w0 = wp[0], w1 = wp[1], w2 = wp[2], w3 = wp[3];
        unpack8(w0, wf); unpack8(w1, wf + 8); unpack8(w2, wf + 16); unpack8(w3, wf + 24);
    }
    float bias[8];
    unpack8(*(const uint4*)(cb + e0), bias);

    float uk[4][8];
#pragma unroll
    for (int k = 0; k < 4; ++k) {
        int tt = t - 3 + k;
        if (tt >= 0) {
            uint4 uv = *(const uint4*)(u + (size_t)(b * LL + tt) * DI + e0);
            unpack8(uv, uk[k]);
        } else {
#pragma unroll
            for (int j = 0; j < 8; ++j) uk[k][j] = 0.f;
        }
    }
    bf16_t out8[8];
#pragma unroll
    for (int j = 0; j < 8; ++j) {
        float a = bias[j];
#pragma unroll
        for (int k = 0; k < 4; ++k) a += wf[j * 4 + k] * uk[k][j];
        a = a / (1.f + __expf(-a));
        out8[j] = __float2bfloat16(a);
    }
    *(uint4*)(uc + (size_t)row * DI + e0) = *(uint4*)out8;
}

// ---------- chunked parallel scan ----------
__global__ __launch_bounds__(256)
void scan_pass1(const bf16_t* __restrict__ uc, const bf16_t* __restrict__ dt,
                const bf16_t* __restrict__ xdbl, const bf16_t* __restrict__ A_log,
                float* __restrict__ aprod, float* __restrict__ hfin, int lgG)
{
    int idx = blockIdx.x * 256 + threadIdx.x;
    int e = idx & (DI - 1);
    int rem = idx >> 11;
    int b = rem & ((1 << lgG) - 1);
    int chunk = rem >> lgG;

    float Aa[NS];
#pragma unroll
    for (int n = 0; n < NS; ++n)
        Aa[n] = -__expf(__bfloat162float(A_log[e * NS + n]));

    float h[NS];
#pragma unroll
    for (int n = 0; n < NS; ++n) h[n] = 0.f;
    float S = 0.f;

    int t0 = chunk * CL;
    const bf16_t* up  = uc   + ((size_t)b * LL + t0) * DI + e;
    const bf16_t* dp  = dt   + ((size_t)b * LL + t0) * DI + e;
    const bf16_t* bcp = xdbl + ((size_t)b * LL + t0) * 96 + 64;

    float nu  = __bfloat162float(*up);
    float ndt = __bfloat162float(*dp);
    uint4 nb0 = *(const uint4*)(bcp);
    uint4 nb1 = *(const uint4*)(bcp + 8);

    for (int t = 0; t < CL; ++t) {
        float cu = nu, cdt = ndt;
        uint4 b0 = nb0, b1 = nb1;
        if (t + 1 < CL) {
            up += DI; dp += DI; bcp += 96;
            nu  = __bfloat162float(*up);
            ndt = __bfloat162float(*dp);
            nb0 = *(const uint4*)(bcp);
            nb1 = *(const uint4*)(bcp + 8);
        }
        float Bv[NS];
        unpack8(b0, Bv); unpack8(b1, Bv + 8);
        float du = cdt * cu;
        S += cdt;
#pragma unroll
        for (int n = 0; n < NS; ++n) {
            float dA = __expf(cdt * Aa[n]);
            h[n] = dA * h[n] + du * Bv[n];
        }
    }
    size_t base = (size_t)(b * NC + chunk) * NS * DI + e;
#pragma unroll
    for (int n = 0; n < NS; ++n) aprod[base + (size_t)n * DI] = __expf(Aa[n] * S);
#pragma unroll
    for (int n = 0; n < NS; ++n) hfin[base + (size_t)n * DI] = h[n];
}

__global__ __launch_bounds__(256)
void scan_pass2(const float* __restrict__ aprod, float* __restrict__ hfin)
{
    int idx = blockIdx.x * 256 + threadIdx.x;
    int e = idx & (DI - 1);
    int rem = idx >> 11;
    int n = rem & (NS - 1);
    int b = rem >> 4;
    float h = 0.f;
    for (int c = 0; c < NC; ++c) {
        size_t a = ((size_t)(b * NC + c) * NS + n) * DI + e;
        float Ap = aprod[a];
        float hf = hfin[a];
        hfin[a] = h;
        h = Ap * h + hf;
    }
}

__global__ __launch_bounds__(256)
void scan_pass3(const bf16_t* __restrict__ uc, const bf16_t* __restrict__ dt,
                const bf16_t* __restrict__ xdbl, bf16_t* __restrict__ zy,
                const bf16_t* __restrict__ A_log, const bf16_t* __restrict__ Dp,
                const float* __restrict__ hin, int lgG)
{
    int idx = blockIdx.x * 256 + threadIdx.x;
    int e = idx & (DI - 1);
    int rem = idx >> 11;
    int b = rem & ((1 << lgG) - 1);
    int chunk = rem >> lgG;

    float Aa[NS];
#pragma unroll
    for (int n = 0; n < NS; ++n)
        Aa[n] = -__expf(__bfloat162float(A_log[e * NS + n]));
    float Dv = __bfloat162float(Dp[e]);

    size_t base = (size_t)(b * NC + chunk) * NS * DI + e;
    float h[NS];
#pragma unroll
    for (int n = 0; n < NS; ++n) h[n] = hin[base + (size_t)n * DI];

    int t0 = chunk * CL;
    const bf16_t* up  = uc   + ((size_t)b * LL + t0) * DI + e;
    const bf16_t* dp  = dt   + ((size_t)b * LL + t0) * DI + e;
    const bf16_t* zp  = zy   + ((size_t)b * LL + t0) * DI + e;
    const bf16_t* bcp = xdbl + ((size_t)b * LL + t0) * 96 + 64;
    bf16_t*       yp  = zy   + ((size_t)b * LL + t0) * DI + e;

    float nu  = __bfloat162float(*up);
    float ndt = __bfloat162float(*dp);
    float nz  = __bfloat162float(*zp);
    uint4 nb0 = *(const uint4*)(bcp);
    uint4 nb1 = *(const uint4*)(bcp + 8);
    uint4 nc0 = *(const uint4*)(bcp + 16);
    uint4 nc1 = *(const uint4*)(bcp + 24);

    for (int t = 0; t < CL; ++t) {
        float cu = nu, cdt = ndt, cz = nz;
        uint4 b0 = nb0, b1 = nb1, c0 = nc0, c1 = nc1;
        if (t + 1 < CL) {
            up += DI; dp += DI; zp += DI; bcp += 96;
            nu  = __bfloat162float(*up);
            ndt = __bfloat162float(*dp);
            nz  = __bfloat162float(*zp);
            nb0 = *(const uint4*)(bcp);
            nb1 = *(const uint4*)(bcp + 8);
            nc0 = *(const uint4*)(bcp + 16);
            nc1 = *(const uint4*)(bcp + 24);
        }
        float Bv[NS], Cv[NS];
        unpack8(b0, Bv); unpack8(b1, Bv + 8);
        unpack8(c0, Cv); unpack8(c1, Cv + 8);

        float du = cdt * cu;
        float yv = 0.f;
#pragma unroll
        for (int n = 0; n < NS; ++n) {
            float dA = __expf(cdt * Aa[n]);
            h[n] = dA * h[n] + du * Bv[n];
            yv += h[n] * Cv[n];
        }
        float sil  = cz / (1.f + __expf(-cz));
        float outv = (yv + cu * Dv) * sil;
        *yp = __float2bfloat16(outv);
        yp += DI;
    }
}

// ---------- serial scan fallback ----------
__global__ __launch_bounds__(64)
void scan_kernel(const bf16_t* __restrict__ uc,
                 const bf16_t* __restrict__ dt,
                 const bf16_t* __restrict__ xdbl,
                 bf16_t* __restrict__ zy,
                 const bf16_t* __restrict__ A_log,
                 const bf16_t* __restrict__ Dp)
{
    int idx = blockIdx.x * 64 + threadIdx.x;
    int e = idx & (DI - 1);
    int b = idx >> 11;

    float Aa[NS];
#pragma unroll
    for (int n = 0; n < NS; ++n)
        Aa[n] = -__expf(__bfloat162float(A_log[e * NS + n]));
    float Dv = __bfloat162float(Dp[e]);
    float h[NS];
#pragma unroll
    for (int n = 0; n < NS; ++n) h[n] = 0.f;

    const bf16_t* up  = uc   + (size_t)b * LL * DI + e;
    const bf16_t* dp  = dt   + (size_t)b * LL * DI + e;
    const bf16_t* zp  = zy   + (size_t)b * LL * DI + e;
    const bf16_t* bcp = xdbl + (size_t)b * LL * 96 + 64;
    bf16_t*       yp  = zy   + (size_t)b * LL * DI + e;

    float nu  = __bfloat162float(*up);
    float ndt = __bfloat162float(*dp);
    float nz  = __bfloat162float(*zp);
    uint4 nb0 = *(const uint4*)(bcp);
    uint4 nb1 = *(const uint4*)(bcp + 8);
    uint4 nc0 = *(const uint4*)(bcp + 16);
    uint4 nc1 = *(const uint4*)(bcp + 24);

    for (int t = 0; t < LL; ++t) {
        float cu = nu, cdt = ndt, cz = nz;
        uint4 b0 = nb0, b1 = nb1, c0 = nc0, c1 = nc1;
        if (t + 1 < LL) {
            up += DI; dp += DI; zp += DI; bcp += 96;
            nu  = __bfloat162float(*up);
            ndt = __bfloat162float(*dp);
            nz  = __bfloat162float(*zp);
            nb0 = *(const uint4*)(bcp);
            nb1 = *(const uint4*)(bcp + 8);
            nc0 = *(const uint4*)(bcp + 16);
            nc1 = *(const uint4*)(bcp + 24);
        }
        float Bv[NS], Cv[NS];
        unpack8(b0, Bv); unpack8(b1, Bv + 8);
        unpack8(c0, Cv); unpack8(c1, Cv + 8);

        float du = cdt * cu;
        float yv = 0.f;
#pragma unroll
        for (int n = 0; n < NS; ++n) {
            float dA = __expf(cdt * Aa[n]);
            h[n] = dA * h[n] + du * Bv[n];
            yv += h[n] * Cv[n];
        }
        float sil  = cz / (1.f + __expf(-cz));
        float outv = (yv + cu * Dv) * sil;
        *yp = __float2bfloat16(outv);
        yp += DI;
    }
}

// ---------- launcher ----------
extern "C" void kernel_launch(void* const* d_in, const int* in_sizes, int n_in,
                              void* d_out, int out_size, void* d_ws, size_t ws_size,
                              hipStream_t stream)
{
    char* ws = (char*)d_ws;
    int* flag = (int*)ws;
    size_t cur = 256;
    auto alloc = [&](size_t bytes) { bf16_t* p = (bf16_t*)(ws + cur); cur += bytes; return p; };

    // canonical bf16 copies (~44.7 MiB). xb+w_in (24 MiB) are dead after in_proj
    // when G==4 and get reused for split-K partials then scan scratch.
    const size_t o_xb = cur;
    bf16_t* xb   = alloc((size_t)MTOK * DM * 2);      // 16 MiB
    bf16_t* w_in = alloc((size_t)2 * DI * DM * 2);    //  8 MiB
    bf16_t* w_o  = alloc((size_t)DM * DI * 2);
    bf16_t* w_l1 = alloc((size_t)DFF * DM * 2);
    bf16_t* w_l2 = alloc((size_t)DM * DFF * 2);
    bf16_t* w_xp = alloc((size_t)96 * DI * 2);
    bf16_t* w_dt = alloc((size_t)DI * DTR * 2);
    bf16_t* cw   = alloc((size_t)DI * 4 * 2);
    bf16_t* cb   = alloc((size_t)DI * 2);
    bf16_t* dpb  = alloc((size_t)DI * 2);
    bf16_t* alog = alloc((size_t)DI * NS * 2);
    bf16_t* dd   = alloc((size_t)DI * 2);
    bf16_t* l1b  = alloc((size_t)DFF * 2);
    bf16_t* l2b  = alloc((size_t)DM * 2 + 2048);
    cur = (cur + 255) & ~(size_t)255;
    const size_t o_pipe = cur;

    detect_dtype_kernel<<<1, 256, 0, stream>>>((const unsigned*)d_in[0], flag);

    {
        CvtDesc d;
        const void* ss[14] = { d_in[0], d_in[1], d_in[9], d_in[10], d_in[12], d_in[4],
                               d_in[5], d_in[2], d_in[3], d_in[6], d_in[7], d_in[8],
                               d_in[11], d_in[13] };
        bf16_t* dd_[14]    = { xb, w_in, w_o, w_l1, w_l2, w_xp,
                               w_dt, cw, cb, dpb, alog, dd, l1b, l2b };
        size_t  nn[14]     = { (size_t)MTOK*DM, (size_t)2*DI*DM, (size_t)DM*DI,
                               (size_t)DFF*DM, (size_t)DM*DFF, (size_t)96*DI,
                               (size_t)DI*DTR, (size_t)DI*4, (size_t)DI, (size_t)DI,
                               (size_t)DI*NS, (size_t)DI, (size_t)DFF, (size_t)DM };
        int c = 0; d.cum[0] = 0;
        for (int i = 0; i < 14; ++i) {
            d.src[i] = ss[i]; d.dst[i] = dd_[i];
            c += (int)(nn[i] / 8); d.cum[i + 1] = c;
        }
        convert_all<<<(c + 255) / 256, 256, 0, stream>>>(d, flag, c);
    }

    auto pipe = [&](int G) { return (size_t)G * LL * 96 * 2 + 3ull * G * LL * DI * 2; };
    auto scr  = [&](int G) { return 2ull * G * NC * NS * DI * 4; };           // scan scratch
    auto spk  = [&](int G) { return (size_t)KS * G * LL * 96 * 4; };          // splitk partials

    // scratch placement: G=4 -> reuse dead xb+w_in region (24 MiB >= 16.8/12.6);
    // G<4 -> tail after pipe (xb still live across group iterations).
    int G; bool chunked; size_t scr_off;
    if      (ws_size >= o_pipe + pipe(4))                             { G = 4; chunked = true;  scr_off = o_xb; }
    else if (ws_size >= o_pipe + pipe(2) + scr(2) + spk(2))           { G = 2; chunked = true;  scr_off = o_pipe + pipe(2); }
    else if (ws_size >= o_pipe + pipe(1) + scr(1) + spk(1))           { G = 1; chunked = true;  scr_off = o_pipe + pipe(1); }
    else                                                              { G = 1; chunked = false; scr_off = o_pipe + pipe(1); }
    const int lgG = (G == 4) ? 2 : (G == 2 ? 1 : 0);

    for (int g0 = 0; g0 < BB; g0 += G) {
        const int    Mg      = G * LL;
        const size_t xdbl_sz = (size_t)Mg * 96 * 2;
        const size_t big     = (size_t)Mg * DI * 2;

        bf16_t* xdbl = (bf16_t*)(ws + o_pipe);
        bf16_t* ubuf = (bf16_t*)(ws + o_pipe + xdbl_sz);
        bf16_t* dtb  = ubuf;
        bf16_t* zbuf = (bf16_t*)(ws + o_pipe + xdbl_sz + big);
        bf16_t* uc   = (bf16_t*)(ws + o_pipe + xdbl_sz + 2 * big);
        bf16_t* my   = uc;
        bf16_t* hh   = (bf16_t*)(ws + o_pipe);
        float*  xpp  = (float*)(ws + scr_off);             // splitk partials (dead before scan)

        const bf16_t* x_g = xb + (size_t)g0 * LL * DM;

        dim3 blk(256);
        const int gx = Mg / TM;

        // 1. in_proj merged (N=4096): cols<2048 -> ubuf, cols>=2048 -> zbuf
        gemm_bt<bf16_t, 0, false, false><<<dim3(gx, (2 * DI) / TN), blk, 0, stream>>>(
            x_g, DM, w_in, DM, ubuf, DI, zbuf, DI, nullptr, Mg, 2 * DI, DM, nullptr, 0);
        // 2. depthwise conv + SiLU -> uc
        conv_silu_kernel<<<Mg, 256, 0, stream>>>(ubuf, cw, cb, uc, Mg);
        // 3. x_proj split-K -> partials -> xdbl
        gemm_xproj_splitk<<<dim3(gx, 1, KS), blk, 0, stream>>>(uc, w_xp, xpp, Mg);
        xproj_reduce<<<(Mg * 96 + 255) / 256, 256, 0, stream>>>(xpp, xdbl, Mg);
        // 4. dt_proj + softplus -> dtb
        gemm_bt<bf16_t, 3, false, false><<<dim3(gx, DI / TN), blk, 0, stream>>>(
            xdbl, 96, w_dt, DTR, dtb, DI, nullptr, 0, dpb, Mg, DI, DTR, nullptr, 0);
        // 5. selective scan + gating; y overwrites zbuf
        if (chunked) {
            float* aprod = (float*)(ws + scr_off);
            float* hfin  = (float*)(ws + scr_off + (size_t)G * NC * NS * DI * 4);
            scan_pass1<<<G * 128, 256, 0, stream>>>(uc, dtb, xdbl, alog, aprod, hfin, lgG);
            scan_pass2<<<G * 128, 256, 0, stream>>>(aprod, hfin);
            scan_pass3<<<G * 128, 256, 0, stream>>>(uc, dtb, xdbl, zbuf, alog, dd, hfin, lgG);
        } else {
            scan_kernel<<<(G * DI) / 64, 64, 0, stream>>>(uc, dtb, xdbl, zbuf, alog, dd);
        }
        // 6. out_proj -> my
        gemm_bt<bf16_t, 0, false, false><<<dim3(gx, DM / TN), blk, 0, stream>>>(
            zbuf, DI, w_o, DI, my, DM, nullptr, 0, nullptr, Mg, DM, DI, nullptr, 0);
        // 7. lin1 + bias + relu -> hh
        gemm_bt<bf16_t, 2, false, false><<<dim3(gx, DFF / TN), blk, 0, stream>>>(
            my, DM, w_l1, DM, hh, DFF, nullptr, 0, l1b, Mg, DFF, DM, nullptr, 0);
        // 8. lin2 + bias -> d_out (dtype per flag)
        gemm_bt<bf16_t, 1, true, false><<<dim3(gx, DM / TN), blk, 0, stream>>>(
            hh, DFF, w_l2, DFF, (bf16_t*)d_out, DM, nullptr, 0, l2b, Mg, DM, DFF,
            (const int*)ws, g0 * LL);
    }
}